// Round 1
// baseline (45.636 us; speedup 1.0000x reference)
//
#include <hip/hip_runtime.h>
#include <math.h>

#define NB 30          // NUM_BINS
#define PV 32          // padded per-column stride (global param tables)
#define PL 33          // padded per-column stride (LDS; bank-conflict-free)
#define VMAX 512

// Static device-global param tables: cumwidths, cumheights, derivatives.
// [v*PV + k], k=0..30 valid, k=31 = +big sentinel for the binary search.
__device__ float g_cw[VMAX * PV];
__device__ float g_ch[VMAX * PV];
__device__ float g_dv[VMAX * PV];

__device__ __forceinline__ void cum_from_unnorm(const float* __restrict__ u,
                                                int v, float min_size,
                                                float* __restrict__ dst) {
    float r[NB];
#pragma unroll
    for (int k = 0; k < NB; ++k) r[k] = u[v * NB + k];
    float m = r[0];
#pragma unroll
    for (int k = 1; k < NB; ++k) m = fmaxf(m, r[k]);
    float e[NB];
    float s = 0.f;
#pragma unroll
    for (int k = 0; k < NB; ++k) { e[k] = __expf(r[k] - m); s += e[k]; }
    const float fac = (1.0f - min_size * (float)NB) / s;
    float run = 0.f;
    dst[v * PV + 0] = 0.0f;                      // lower bound LI/LO = 0
#pragma unroll
    for (int k = 0; k < NB; ++k) {
        run += min_size + fac * e[k];            // floor + scaled softmax, cumsum
        dst[v * PV + k + 1] = run;               // (upper-lower)*cp+lower = cp
    }
    dst[v * PV + 31] = 3.0e38f;                  // sentinel
}

__global__ void rqs_params_kernel(const float* __restrict__ uw,
                                  const float* __restrict__ uh,
                                  const float* __restrict__ ud, int V) {
    int v = blockIdx.x * 64 + threadIdx.x;
    if (v >= V) return;
    cum_from_unnorm(uw, v, 0.001f, g_cw);        // MIN_BW
    cum_from_unnorm(uh, v, 0.001f, g_ch);        // MIN_BH
    // boundary derivative: MIN_D + softplus(log(exp(1-MIN_D)-1)) == 1 (up to fp)
    const float cc = logf(expf(0.999f) - 1.0f);
    const float edge = 0.001f + log1pf(expf(cc));
    g_dv[v * PV + 0] = edge;
#pragma unroll
    for (int k = 1; k < NB; ++k)
        g_dv[v * PV + k] = 0.001f + log1pf(expf(ud[v * (NB - 1) + k - 1]));
    g_dv[v * PV + NB] = edge;
    g_dv[v * PV + 31] = 3.0e38f;
}

__global__ __launch_bounds__(256) void rqs_main_kernel(
        const float* __restrict__ x_in, float* __restrict__ out,
        float* __restrict__ lad, int B, int V, int nct, int rowTiles) {
    __shared__ float cwS[64 * PL];
    __shared__ float chS[64 * PL];
    __shared__ float dvS[64 * PL];

    const int tid = threadIdx.x;
    const int colTile = blockIdx.x % nct;
    const int rowBlk  = blockIdx.x / nct;
    const int colbase = colTile * 64;

    // Stage 64 columns' params into LDS (stride 33 -> conflict-free reads).
    for (int i = tid; i < 64 * PV; i += 256) {
        const int c = i >> 5, k = i & 31;
        const int gi = (colbase + c) * PV + k;
        const int li = c * PL + k;
        cwS[li] = g_cw[gi];
        chS[li] = g_ch[gi];
        dvS[li] = g_dv[gi];
    }
    __syncthreads();

    const int c = tid & 63;
    const int rsub = tid >> 6;
    const int col = colbase + c;
    const float* __restrict__ cb  = &cwS[c * PL];
    const float* __restrict__ chp = &chS[c * PL];
    const float* __restrict__ dvp = &dvS[c * PL];

    for (int row = rowBlk * 4 + rsub; row < B; row += rowTiles * 4) {
        const float x = x_in[(size_t)row * V + col];
        const float xc = fminf(fmaxf(x, 0.0f), 1.0f);

        // branchless binary search over 31 boundaries (+inf sentinel at 31):
        // largest j with cb[j] <= xc
        int j = (cb[16] <= xc) ? 16 : 0;
        j += (cb[j +  8] <= xc) ?  8 : 0;
        j += (cb[j +  4] <= xc) ?  4 : 0;
        j += (cb[j +  2] <= xc) ?  2 : 0;
        j += (cb[j +  1] <= xc) ?  1 : 0;
        const int bin = min(j, NB - 1);

        const float cwl = cb[bin],  cwr = cb[bin + 1];
        const float chl = chp[bin], chr = chp[bin + 1];
        const float d0  = dvp[bin], d1  = dvp[bin + 1];

        const float w = cwr - cwl;
        const float h = chr - chl;
        const float winv = 1.0f / w;
        const float delta = h * winv;
        const float theta = (xc - cwl) * winv;
        const float omt = 1.0f - theta;
        const float t1mt = theta * omt;
        const float th2 = theta * theta;
        const float den = delta + (d0 + d1 - 2.0f * delta) * t1mt;
        const float out_in = chl + h * (delta * th2 + d0 * t1mt) / den;
        const float dd = delta * delta;
        const float numd = dd * (d1 * th2 + 2.0f * delta * t1mt + d0 * omt * omt);
        const float lad_in = __logf(numd) - 2.0f * __logf(den);

        const bool inside = (x >= 0.0f) && (x <= 1.0f);
        // outside: out = LO + (x-LI)*DERIV_OUT = x (DERIV_OUT==1), lad = 0
        out[(size_t)row * V + col] = inside ? out_in : x;
        lad[(size_t)row * V + col] = inside ? lad_in : 0.0f;
    }
}

extern "C" void kernel_launch(void* const* d_in, const int* in_sizes, int n_in,
                              void* d_out, int out_size, void* d_ws, size_t ws_size,
                              hipStream_t stream) {
    const float* x  = (const float*)d_in[0];
    const float* uw = (const float*)d_in[1];
    const float* uh = (const float*)d_in[2];
    const float* ud = (const float*)d_in[3];

    const int V = in_sizes[1] / NB;          // 512
    const int B = in_sizes[0] / V;           // 16384

    float* out = (float*)d_out;
    float* lad = out + (size_t)B * V;

    rqs_params_kernel<<<(V + 63) / 64, 64, 0, stream>>>(uw, uh, ud, V);

    const int nct = V / 64;                  // column tiles (8)
    const int rowTiles = 128;                // grid = 1024 blocks, 4 blk/CU
    rqs_main_kernel<<<nct * rowTiles, 256, 0, stream>>>(x, out, lad, B, V, nct, rowTiles);
}

// Round 2
// 38.524 us; speedup vs baseline: 1.1846x; 1.1846x over previous
//
#include <hip/hip_runtime.h>
#include <math.h>

#define NB 30            // NUM_BINS
#define PKG 96           // packed floats per column in global (31 triples + 3 pad)
#define PKS 99           // packed stride in LDS (99 mod 32 = 3, gcd(3,32)=1 -> no pathological banks)
#define VMAX 512

// Packed per-column params: triples (cw[k], ch[k], dv[k]) for k=0..30, slot 93 = search sentinel.
__device__ float g_pk[VMAX * PKG];

__device__ __forceinline__ float softplus_safe(float x) {
    return fmaxf(x, 0.0f) + log1pf(__expf(-fabsf(x)));
}

__device__ __forceinline__ void cum_from_unnorm(const float* __restrict__ u,
                                                int v, float min_size,
                                                float* __restrict__ dst /*31*/) {
    float r[NB];
#pragma unroll
    for (int k = 0; k < NB; ++k) r[k] = u[v * NB + k];
    float m = r[0];
#pragma unroll
    for (int k = 1; k < NB; ++k) m = fmaxf(m, r[k]);
    float e[NB];
    float s = 0.f;
#pragma unroll
    for (int k = 0; k < NB; ++k) { e[k] = __expf(r[k] - m); s += e[k]; }
    const float fac = (1.0f - min_size * (float)NB) / s;
    float run = 0.f;
    dst[0] = 0.0f;
#pragma unroll
    for (int k = 0; k < NB; ++k) {
        run += min_size + fac * e[k];
        dst[k + 1] = run;
    }
}

__global__ void rqs_params_kernel(const float* __restrict__ uw,
                                  const float* __restrict__ uh,
                                  const float* __restrict__ ud, int V) {
    int v = blockIdx.x * 64 + threadIdx.x;
    if (v >= V) return;
    float cw[NB + 1], ch[NB + 1], dv[NB + 1];
    cum_from_unnorm(uw, v, 0.001f, cw);   // MIN_BW
    cum_from_unnorm(uh, v, 0.001f, ch);   // MIN_BH
    dv[0] = 1.0f;                          // MIN_D + softplus(log(exp(1-MIN_D)-1)) == 1
    dv[NB] = 1.0f;
#pragma unroll
    for (int k = 1; k < NB; ++k)
        dv[k] = 0.001f + softplus_safe(ud[v * (NB - 1) + k - 1]);

    float* d = &g_pk[v * PKG];
#pragma unroll
    for (int k = 0; k <= NB; ++k) {
        d[3 * k + 0] = cw[k];
        d[3 * k + 1] = ch[k];
        d[3 * k + 2] = dv[k];
    }
    d[93] = 3.0e38f;   // sentinel cw[31] for the binary search
    d[94] = 0.0f;
    d[95] = 0.0f;
}

__global__ __launch_bounds__(256) void rqs_main_kernel(
        const float* __restrict__ x_in, float* __restrict__ out,
        float* __restrict__ lad, int B, int V, int nct, int rowTiles) {
    __shared__ float pkS[64 * PKS];

    const int tid = threadIdx.x;
    const int colTile = blockIdx.x % nct;
    const int rowBlk  = blockIdx.x / nct;
    const int colbase = colTile * 64;

    // Stage 64 columns (96 floats each) into LDS: float4 global loads, scalar LDS writes.
    for (int i = tid; i < 64 * (PKG / 4); i += 256) {
        const int c = i / (PKG / 4);
        const int q = i - c * (PKG / 4);
        const float4 val = *(const float4*)&g_pk[(size_t)(colbase + c) * PKG + q * 4];
        float* dst = &pkS[c * PKS + q * 4];
        dst[0] = val.x; dst[1] = val.y; dst[2] = val.z; dst[3] = val.w;
    }
    __syncthreads();

    const int c = tid & 63;
    const int w = tid >> 6;                 // wave id 0..3
    const int col = colbase + c;
    const float* __restrict__ pc = &pkS[c * PKS];

    const int rowStride = rowTiles * 16;    // rows per full grid pass

    for (int base = rowBlk * 16; base < B; base += rowStride) {
        const int r0 = base + w * 4;

        float xv[4], xc[4];
        int jj[4];                           // bin index premultiplied by 3 (triple offset)
#pragma unroll
        for (int u = 0; u < 4; ++u) {
            const int row = r0 + u;
            xv[u] = (row < B) ? x_in[(size_t)row * V + col] : 0.5f;
            xc[u] = fminf(fmaxf(xv[u], 0.0f), 1.0f);
        }

        // step-major branchless binary search: 4 independent LDS chains in flight
#pragma unroll
        for (int u = 0; u < 4; ++u) jj[u] = (pc[48] <= xc[u]) ? 48 : 0;          // j=16
#pragma unroll
        for (int u = 0; u < 4; ++u) jj[u] += (pc[jj[u] + 24] <= xc[u]) ? 24 : 0; // +8
#pragma unroll
        for (int u = 0; u < 4; ++u) jj[u] += (pc[jj[u] + 12] <= xc[u]) ? 12 : 0; // +4
#pragma unroll
        for (int u = 0; u < 4; ++u) jj[u] += (pc[jj[u] +  6] <= xc[u]) ?  6 : 0; // +2
#pragma unroll
        for (int u = 0; u < 4; ++u) jj[u] += (pc[jj[u] +  3] <= xc[u]) ?  3 : 0; // +1
#pragma unroll
        for (int u = 0; u < 4; ++u) jj[u] = min(jj[u], 3 * (NB - 1));

        float cwl[4], chl[4], d0[4], cwr[4], chr[4], d1[4];
#pragma unroll
        for (int u = 0; u < 4; ++u) {
            const float* p = pc + jj[u];
            cwl[u] = p[0]; chl[u] = p[1]; d0[u] = p[2];   // ds_read2_b32 x3
            cwr[u] = p[3]; chr[u] = p[4]; d1[u] = p[5];
        }

#pragma unroll
        for (int u = 0; u < 4; ++u) {
            const int row = r0 + u;
            if (row >= B) continue;
            const float wd = cwr[u] - cwl[u];
            const float h  = chr[u] - chl[u];
            const float winv = __builtin_amdgcn_rcpf(wd);
            const float delta = h * winv;
            const float theta = (xc[u] - cwl[u]) * winv;
            const float omt = 1.0f - theta;
            const float t1mt = theta * omt;
            const float th2 = theta * theta;
            const float den = delta + (d0[u] + d1[u] - 2.0f * delta) * t1mt;
            const float dinv = __builtin_amdgcn_rcpf(den);
            const float out_in = chl[u] + h * (delta * th2 + d0[u] * t1mt) * dinv;
            const float dd = delta * delta;
            const float numd = dd * (d1[u] * th2 + 2.0f * delta * t1mt + d0[u] * omt * omt);
            const float lad_in = __logf(numd * dinv * dinv);

            const bool inside = (xv[u] >= 0.0f) && (xv[u] <= 1.0f);
            out[(size_t)row * V + col] = inside ? out_in : xv[u];  // outside: slope-1 identity
            lad[(size_t)row * V + col] = inside ? lad_in : 0.0f;
        }
    }
}

extern "C" void kernel_launch(void* const* d_in, const int* in_sizes, int n_in,
                              void* d_out, int out_size, void* d_ws, size_t ws_size,
                              hipStream_t stream) {
    const float* x  = (const float*)d_in[0];
    const float* uw = (const float*)d_in[1];
    const float* uh = (const float*)d_in[2];
    const float* ud = (const float*)d_in[3];

    const int V = in_sizes[1] / NB;          // 512
    const int B = in_sizes[0] / V;           // 16384

    float* out = (float*)d_out;
    float* lad = out + (size_t)B * V;

    rqs_params_kernel<<<(V + 63) / 64, 64, 0, stream>>>(uw, uh, ud, V);

    const int nct = V / 64;                  // 8 column tiles
    const int rowTiles = 192;                // 1536 blocks = 6 blocks/CU (LDS cap)
    rqs_main_kernel<<<nct * rowTiles, 256, 0, stream>>>(x, out, lad, B, V, nct, rowTiles);
}

// Round 3
// 35.342 us; speedup vs baseline: 1.2913x; 1.0900x over previous
//
#include <hip/hip_runtime.h>
#include <math.h>

#define NB 30           // NUM_BINS
#define PS 99           // per-column LDS stride in floats (99 mod 32 = 3, conflict-friendly)
#define TPB 256

__device__ __forceinline__ float softplus_f(float x) {
    return fmaxf(x, 0.0f) + log1pf(__expf(-fabsf(x)));
}

// softmax -> min-size floor -> cumsum for one column; writes dst[3*k], k=0..NB.
__device__ __forceinline__ void stage_cum(const float* __restrict__ u, int v,
                                          float* __restrict__ dst) {
    float r[NB];
#pragma unroll
    for (int k = 0; k < NB; ++k) r[k] = u[v * NB + k];
    float m = r[0];
#pragma unroll
    for (int k = 1; k < NB; ++k) m = fmaxf(m, r[k]);
    float s = 0.f;
#pragma unroll
    for (int k = 0; k < NB; ++k) s += __expf(r[k] - m);
    const float fac = (1.0f - 0.001f * (float)NB) / s;
    float run = 0.f;
    dst[0] = 0.f;
#pragma unroll
    for (int k = 0; k < NB; ++k) {
        run += 0.001f + fac * __expf(r[k] - m);
        dst[3 * (k + 1)] = run;
    }
}

template <int VC, bool EXACT>
__global__ __launch_bounds__(TPB, 4) void rqs_fused_kernel(
        const float* __restrict__ x_in,
        const float* __restrict__ uw,
        const float* __restrict__ uh,
        const float* __restrict__ ud,
        float* __restrict__ out,
        float* __restrict__ lad,
        int B, int Vrt, int nct, int rowTiles) {
    const int V = VC ? VC : Vrt;

    __shared__ float pkS[64 * PS];   // 64 cols x (31 triples cw,ch,dv + sentinel)

    const int tid = threadIdx.x;
    const int colTile = blockIdx.x % nct;
    const int rowBlk  = blockIdx.x / nct;
    const int colbase = colTile * 64;

    // ---- fused per-column param computation (threads 0..63, one column each) ----
    if (tid < 64) {
        const int v = colbase + tid;
        float* pcw = &pkS[tid * PS];
        stage_cum(uw, v, pcw);           // cumwidths  -> pc[3k]
        stage_cum(uh, v, pcw + 1);       // cumheights -> pc[3k+1]
        pcw[2] = 1.0f;                   // edge deriv: MIN_D + softplus(c) == 1
        pcw[3 * NB + 2] = 1.0f;
#pragma unroll
        for (int k = 1; k < NB; ++k)
            pcw[3 * k + 2] = 0.001f + softplus_f(ud[v * (NB - 1) + k - 1]);
        pcw[93] = 3.0e38f;               // search sentinel (cw slot 31)
    }
    __syncthreads();

    const int c = tid & 63;
    const int w = tid >> 6;              // wave id 0..3
    const int col = colbase + c;
    const float* __restrict__ pc = &pkS[c * PS];

    // hoist search levels 1-3 boundaries into registers (column fixed per thread)
    const float c12 = pc[12], c24 = pc[24], c36 = pc[36], c48 = pc[48];
    const float c60 = pc[60], c72 = pc[72], c84 = pc[84];

    const int passRows = 32;             // 4 waves x 8 rows

    for (int base = rowBlk * passRows; base < B; base += rowTiles * passRows) {
        const int r0 = base + w * 8;

        float xv[8], xc[8];
        int jj[8];
#pragma unroll
        for (int u = 0; u < 8; ++u) {
            const int row = r0 + u;
            const bool ok = EXACT || (row < B);
            xv[u] = ok ? __builtin_nontemporal_load(&x_in[(size_t)row * V + col]) : 0.5f;
        }
#pragma unroll
        for (int u = 0; u < 8; ++u) xc[u] = fminf(fmaxf(xv[u], 0.0f), 1.0f);

        // levels 1-3: register cndmask tree (no LDS, short dep chain)
#pragma unroll
        for (int u = 0; u < 8; ++u) {
            const float xq = xc[u];
            const bool b1 = (c48 <= xq);
            const float l2 = b1 ? c72 : c24;
            const bool b2 = (l2 <= xq);
            const float t0 = b2 ? c36 : c12;
            const float t1 = b2 ? c84 : c60;
            const float l3 = b1 ? t1 : t0;
            const bool b3 = (l3 <= xq);
            jj[u] = (b1 ? 48 : 0) + (b2 ? 24 : 0) + (b3 ? 12 : 0);
        }
        // levels 4-5: two dependent LDS reads, step-major (8 chains in flight)
#pragma unroll
        for (int u = 0; u < 8; ++u) jj[u] += (pc[jj[u] + 6] <= xc[u]) ? 6 : 0;
#pragma unroll
        for (int u = 0; u < 8; ++u) jj[u] += (pc[jj[u] + 3] <= xc[u]) ? 3 : 0;
#pragma unroll
        for (int u = 0; u < 8; ++u) jj[u] = min(jj[u], 3 * (NB - 1));

        // two groups of 4: fetch params (3x ds_read2), compute, store
#pragma unroll
        for (int g = 0; g < 2; ++g) {
            float cwl[4], cwr[4], chl[4], chr[4], d0[4], d1[4];
#pragma unroll
            for (int q = 0; q < 4; ++q) {
                const float* p = pc + jj[g * 4 + q];
                cwl[q] = p[0]; cwr[q] = p[3];
                chl[q] = p[1]; chr[q] = p[4];
                d0[q]  = p[2]; d1[q]  = p[5];
            }
#pragma unroll
            for (int q = 0; q < 4; ++q) {
                const int u = g * 4 + q;
                const int row = r0 + u;
                const bool ok = EXACT || (row < B);
                const float wd = cwr[q] - cwl[q];
                const float h  = chr[q] - chl[q];
                const float winv = __builtin_amdgcn_rcpf(wd);
                const float delta = h * winv;
                const float theta = (xc[u] - cwl[q]) * winv;
                const float omt = 1.0f - theta;
                const float t1mt = theta * omt;
                const float th2 = theta * theta;
                const float den = delta + (d0[q] + d1[q] - 2.0f * delta) * t1mt;
                const float dinv = __builtin_amdgcn_rcpf(den);
                const float out_in = chl[q] + h * (delta * th2 + d0[q] * t1mt) * dinv;
                const float numd = delta * delta *
                    (d1[q] * th2 + 2.0f * delta * t1mt + d0[q] * omt * omt);
                const float lad_in = __logf(numd * dinv * dinv);

                const bool inside = (xv[u] >= 0.0f) && (xv[u] <= 1.0f);
                if (ok) {
                    const size_t idx = (size_t)row * V + col;
                    out[idx] = inside ? out_in : xv[u];   // outside: slope-1 identity
                    lad[idx] = inside ? lad_in : 0.0f;
                }
            }
        }
    }
}

extern "C" void kernel_launch(void* const* d_in, const int* in_sizes, int n_in,
                              void* d_out, int out_size, void* d_ws, size_t ws_size,
                              hipStream_t stream) {
    const float* x  = (const float*)d_in[0];
    const float* uw = (const float*)d_in[1];
    const float* uh = (const float*)d_in[2];
    const float* ud = (const float*)d_in[3];

    const int V = in_sizes[1] / NB;          // 512
    const int B = in_sizes[0] / V;           // 16384

    float* out = (float*)d_out;
    float* lad = out + (size_t)B * V;

    if (V == 512 && (B % 32) == 0) {
        const int nct = 512 / 64;            // 8 column tiles
        const int rowTiles = (B / 32 + 3) / 4 >= 128 ? 128 : (B / 32); // 1024 blocks, 4 exact passes
        rqs_fused_kernel<512, true><<<nct * rowTiles, TPB, 0, stream>>>(
            x, uw, uh, ud, out, lad, B, V, nct, rowTiles);
    } else {
        const int nct = V / 64;
        int rowTiles = (B + 31) / 32;
        if (rowTiles > 128) rowTiles = 128;
        rqs_fused_kernel<0, false><<<nct * rowTiles, TPB, 0, stream>>>(
            x, uw, uh, ud, out, lad, B, V, nct, rowTiles);
    }
}